// Round 15
// baseline (4186.545 us; speedup 1.0000x reference)
//
#include <hip/hip_runtime.h>
#include <cstdint>
#include <cstddef>

typedef _Float16 h16;
typedef h16 v8h __attribute__((ext_vector_type(8)));
typedef h16 v4h __attribute__((ext_vector_type(4)));
typedef float v4f __attribute__((ext_vector_type(4)));

constexpr int NN = 2048;
constexpr float INV_N = 1.0f / 2048.0f;
constexpr int LP = 72;  // LDS row stride in halves (64 + 8 pad)

#define MFMA16(a, b, c) __builtin_amdgcn_mfma_f32_16x16x32_f16((a), (b), (c), 0, 0, 0)

// ---------------- diagnostic fill ----------------
__global__ void fill_k(float* __restrict__ o, float v, size_t ntot) {
  size_t i = (size_t)blockIdx.x * 256 + threadIdx.x;
  if (i < ntot) o[i] = v;
}

// ---------------- prep kernels ----------------

__global__ void prep_Asplit_k(const float* __restrict__ A,
                              h16* __restrict__ hi, h16* __restrict__ lo) {
  int tid = blockIdx.x * 256 + threadIdx.x;   // 4M
  float v = A[tid] * 2048.0f;
  h16 h = (h16)v;
  hi[tid] = h;
  lo[tid] = (h16)(v - (float)h);
}

// AsT[j][t] = A[t][j]*2048, split
__global__ void prep_AsTsplit_k(const float* __restrict__ A,
                                h16* __restrict__ hi, h16* __restrict__ lo) {
  int tid = blockIdx.x * 256 + threadIdx.x;   // 4M
  int t = tid & 2047, j = tid >> 11;
  float v = A[(size_t)t * NN + j] * 2048.0f;
  h16 h = (h16)v;
  hi[(size_t)j * NN + t] = h;
  lo[(size_t)j * NN + t] = (h16)(v - (float)h);
}

__global__ void prep_x0split_k(const float* __restrict__ x,
                               h16* __restrict__ hi, h16* __restrict__ lo) {
  int tid = blockIdx.x * 256 + threadIdx.x;   // 384*2048
  int n = tid & 2047, c = tid >> 11;
  int ii = c & 1, b = (c >> 1) & 15, lt = c >> 5;
  float v = x[(((size_t)(b * 12 + lt)) * NN + n) * 2 + ii];
  h16 h = (h16)v;
  hi[tid] = h;
  lo[tid] = (h16)(v - (float)h);
}

// Packed folded pool weights in MFMA-fragment order:
// dest tid = (((g*30 + t)*2 + kk)*4 + b)*512 + lane*8 + c
// value = fold(Wp)[o = g*64 + b*16 + (lane&15)][kcol = (t/3)*192 + (t%3)*64 + kk*32 + (lane>>4)*8 + c]
template<int CO>
__global__ void prep_wpack_k(const float* __restrict__ Wp,
                             h16* __restrict__ Ph, h16* __restrict__ Pl) {
  int tid = blockIdx.x * 256 + threadIdx.x;   // CO*1920 elements
  int c = tid & 7;
  int ln = (tid >> 3) & 63;
  int rest = tid >> 9;
  int b = rest & 3;
  int kk = (rest >> 2) & 1;
  int r3 = rest >> 3;           // g*30 + t
  int t = r3 % 30;
  int g = r3 / 30;
  int o = g * 64 + b * 16 + (ln & 15);
  int kcol = (t / 3) * 192 + (t % 3) * 64 + kk * 32 + (ln >> 4) * 8 + c;
  int d = kcol / 192, rem = kcol - d * 192;
  int jb = rem >> 6, i = rem & 63;
  float v;
  if (jb == 0)
    v = Wp[((size_t)((d * 3 + 0) * 66 + i)) * CO + o] -
        Wp[((size_t)((d * 3 + 2) * 66 + i)) * CO + o];
  else if (jb == 1)
    v = Wp[((size_t)((d * 3 + 1) * 66 + i)) * CO + o];
  else
    v = 2.f * Wp[((size_t)((d * 3 + 2) * 66 + i)) * CO + o];
  h16 h = (h16)v;
  Ph[tid] = h;
  Pl[tid] = (h16)(v - (float)h);
}

template<int CO>
__global__ void prep_wx_k(const float* __restrict__ E, const float* __restrict__ Wp,
                          float* __restrict__ Wx) {
  int tid = blockIdx.x * 256 + threadIdx.x;   // 2048*6*CO
  int o = tid & (CO - 1), t6 = (tid / CO) % 6, n = tid / (6 * CO);
  int k = t6 >> 1, ii = t6 & 1;
  float s = 0.f;
  for (int d = 0; d < 10; ++d) {
    float p0 = Wp[((size_t)((d * 3 + 0) * 66 + 64 + ii)) * CO + o];
    float p1 = Wp[((size_t)((d * 3 + 1) * 66 + 64 + ii)) * CO + o];
    float p2 = Wp[((size_t)((d * 3 + 2) * 66 + 64 + ii)) * CO + o];
    float v = (k == 0) ? (p0 - p2) : (k == 1 ? p1 : 2.f * p2);
    s += E[n * 10 + d] * v;
  }
  Wx[tid] = s;
}

template<int CO>
__global__ void prep_b_k(const float* __restrict__ E, const float* __restrict__ bp,
                         float* __restrict__ bv) {
  int tid = blockIdx.x * 256 + threadIdx.x;   // 2048*CO
  int o = tid & (CO - 1), n = tid / CO;
  float s = 0.f;
  for (int d = 0; d < 10; ++d) s += E[n * 10 + d] * bp[d * CO + o];
  bv[tid] = s;
}

// ---------------- split-fp16 MFMA SpMM, BM=64/BN=64, 256 thr (r14 verbatim) ----------------
template<int OM>
__global__ __launch_bounds__(256, 4) void sgemm_k(
    const h16* __restrict__ Ih, const h16* __restrict__ Il,
    const h16* __restrict__ Bh, const h16* __restrict__ Bl,
    float* __restrict__ oF, h16* __restrict__ oH, h16* __restrict__ oL,
    float* __restrict__ xsv, int xoff) {
  const int m0 = blockIdx.x * 64, n0 = blockIdx.y * 64;
  __shared__ __align__(16) h16 sAh[64 * LP], sAl[64 * LP];
  __shared__ __align__(16) h16 sBh[64 * LP], sBl[64 * LP];
  const int tid = threadIdx.x, lane = tid & 63, w = tid >> 6;
  const int wm = w >> 1, wn = w & 1;
  v4f acc[2][2] = {};
  const int sr = tid >> 2, sc = (tid & 3) * 16;
  v8h rah0 = *(const v8h*)(Ih + (size_t)(m0 + sr) * NN + sc);
  v8h rah1 = *(const v8h*)(Ih + (size_t)(m0 + sr) * NN + sc + 8);
  v8h ral0 = *(const v8h*)(Il + (size_t)(m0 + sr) * NN + sc);
  v8h ral1 = *(const v8h*)(Il + (size_t)(m0 + sr) * NN + sc + 8);
  v8h rbh0 = *(const v8h*)(Bh + (size_t)(n0 + sr) * NN + sc);
  v8h rbh1 = *(const v8h*)(Bh + (size_t)(n0 + sr) * NN + sc + 8);
  v8h rbl0 = *(const v8h*)(Bl + (size_t)(n0 + sr) * NN + sc);
  v8h rbl1 = *(const v8h*)(Bl + (size_t)(n0 + sr) * NN + sc + 8);
  for (int kt = 0; kt < NN; kt += 64) {
    __syncthreads();
    *(v8h*)(sAh + sr * LP + sc) = rah0;
    *(v8h*)(sAh + sr * LP + sc + 8) = rah1;
    *(v8h*)(sAl + sr * LP + sc) = ral0;
    *(v8h*)(sAl + sr * LP + sc + 8) = ral1;
    *(v8h*)(sBh + sr * LP + sc) = rbh0;
    *(v8h*)(sBh + sr * LP + sc + 8) = rbh1;
    *(v8h*)(sBl + sr * LP + sc) = rbl0;
    *(v8h*)(sBl + sr * LP + sc + 8) = rbl1;
    __syncthreads();
    if (kt + 64 < NN) {
      const int k2 = kt + 64 + sc;
      rah0 = *(const v8h*)(Ih + (size_t)(m0 + sr) * NN + k2);
      rah1 = *(const v8h*)(Ih + (size_t)(m0 + sr) * NN + k2 + 8);
      ral0 = *(const v8h*)(Il + (size_t)(m0 + sr) * NN + k2);
      ral1 = *(const v8h*)(Il + (size_t)(m0 + sr) * NN + k2 + 8);
      rbh0 = *(const v8h*)(Bh + (size_t)(n0 + sr) * NN + k2);
      rbh1 = *(const v8h*)(Bh + (size_t)(n0 + sr) * NN + k2 + 8);
      rbl0 = *(const v8h*)(Bl + (size_t)(n0 + sr) * NN + k2);
      rbl1 = *(const v8h*)(Bl + (size_t)(n0 + sr) * NN + k2 + 8);
    }
#pragma unroll
    for (int kk = 0; kk < 2; ++kk) {
      const int ko = kk * 32 + (lane >> 4) * 8;
      const int rs = lane & 15;
      v8h Ah0 = *(const v8h*)(sAh + (wm * 32 + rs) * LP + ko);
      v8h Ah1 = *(const v8h*)(sAh + (wm * 32 + 16 + rs) * LP + ko);
      v8h Al0 = *(const v8h*)(sAl + (wm * 32 + rs) * LP + ko);
      v8h Al1 = *(const v8h*)(sAl + (wm * 32 + 16 + rs) * LP + ko);
      v8h Bh0 = *(const v8h*)(sBh + (wn * 32 + rs) * LP + ko);
      v8h Bh1 = *(const v8h*)(sBh + (wn * 32 + 16 + rs) * LP + ko);
      v8h Bl0 = *(const v8h*)(sBl + (wn * 32 + rs) * LP + ko);
      v8h Bl1 = *(const v8h*)(sBl + (wn * 32 + 16 + rs) * LP + ko);
      acc[0][0] = MFMA16(Ah0, Bh0, acc[0][0]);
      acc[0][1] = MFMA16(Ah0, Bh1, acc[0][1]);
      acc[1][0] = MFMA16(Ah1, Bh0, acc[1][0]);
      acc[1][1] = MFMA16(Ah1, Bh1, acc[1][1]);
      acc[0][0] = MFMA16(Al0, Bh0, acc[0][0]);
      acc[0][1] = MFMA16(Al0, Bh1, acc[0][1]);
      acc[1][0] = MFMA16(Al1, Bh0, acc[1][0]);
      acc[1][1] = MFMA16(Al1, Bh1, acc[1][1]);
      acc[0][0] = MFMA16(Ah0, Bl0, acc[0][0]);
      acc[0][1] = MFMA16(Ah0, Bl1, acc[0][1]);
      acc[1][0] = MFMA16(Ah1, Bl0, acc[1][0]);
      acc[1][1] = MFMA16(Ah1, Bl1, acc[1][1]);
    }
  }
  const int l15 = lane & 15, l4 = (lane >> 4) * 4;
#pragma unroll
  for (int ni = 0; ni < 2; ++ni) {
    const int n = n0 + wn * 32 + ni * 16 + l15;
#pragma unroll
    for (int mi = 0; mi < 2; ++mi) {
      const int cb = m0 + wm * 32 + mi * 16 + l4;
      float vv[4];
#pragma unroll
      for (int r = 0; r < 4; ++r) {
        vv[r] = acc[mi][ni][r] * INV_N;
        if constexpr (OM & 1) oF[(size_t)(cb + r) * NN + n] = vv[r];
        if constexpr (OM & 2) {
          h16 h = (h16)vv[r];
          oH[(size_t)(cb + r) * NN + n] = h;
          oL[(size_t)(cb + r) * NN + n] = (h16)(vv[r] - (float)h);
        }
      }
      if constexpr (OM & 4) {
        const int n2 = n & 2047;
        const int xo = xoff + ((n >> 11) << 6);
        v4f pv = {vv[0], vv[1], vv[2], vv[3]};
        *(v4f*)(xsv + ((size_t)(cb >> 6) * 2048 + n2) * 192 + xo + (cb & 63)) = pv;
      }
    }
  }
}

// ---------------- MFMA gate: 1-wave blocks, no LDS, no barriers ----------------
// grid (1024, 2); block 64. Wave owns 32 R-rows x 64 o (gy half). B pre-packed.
__global__ __launch_bounds__(64) void mgate_k(
    const float* __restrict__ xs, const h16* __restrict__ Bph, const h16* __restrict__ Bpl,
    const float* __restrict__ E, const float* __restrict__ bgv,
    const float* __restrict__ Wx, const float* __restrict__ x,
    const float* __restrict__ X1t, const float* __restrict__ X2t,
    float* __restrict__ RHs, float* __restrict__ ubuf,
    h16* __restrict__ HRh, h16* __restrict__ HRl, int lt) {
  const int R0 = blockIdx.x * 32;
  const int gy = blockIdx.y, ob = gy * 64;
  const int bl = R0 >> 11, n0 = R0 & 2047;
  const int lane = threadIdx.x;
  const int rs = lane & 15, q = lane >> 4;
  float e0[10], e1[10];
#pragma unroll
  for (int d = 0; d < 10; ++d) {
    e0[d] = E[(size_t)(n0 + rs) * 10 + d];
    e1[d] = E[(size_t)(n0 + 16 + rs) * 10 + d];
  }
  const float* a0base = xs + (size_t)(R0 + rs) * 192;
  const float* a1base = xs + (size_t)(R0 + 16 + rs) * 192;
  const h16* pbh = Bph + (size_t)gy * 122880 + lane * 8;
  const h16* pbl = Bpl + (size_t)gy * 122880 + lane * 8;
  v4f acc[2][4] = {};
  int d = 0, jb = 0;
  for (int t = 0; t < 30; ++t) {
    const float ed0 = e0[d], ed1 = e1[d];
#pragma unroll
    for (int kk = 0; kk < 2; ++kk) {
      const int co = jb * 64 + kk * 32 + q * 8;
      v4f x00 = *(const v4f*)(a0base + co);
      v4f x01 = *(const v4f*)(a0base + co + 4);
      v4f x10 = *(const v4f*)(a1base + co);
      v4f x11 = *(const v4f*)(a1base + co + 4);
      v8h Ah0, Al0, Ah1, Al1;
#pragma unroll
      for (int i = 0; i < 4; ++i) {
        float v = x00[i] * ed0; h16 hh = (h16)v; Ah0[i] = hh; Al0[i] = (h16)(v - (float)hh);
        v = x01[i] * ed0; hh = (h16)v; Ah0[4 + i] = hh; Al0[4 + i] = (h16)(v - (float)hh);
        v = x10[i] * ed1; hh = (h16)v; Ah1[i] = hh; Al1[i] = (h16)(v - (float)hh);
        v = x11[i] * ed1; hh = (h16)v; Ah1[4 + i] = hh; Al1[4 + i] = (h16)(v - (float)hh);
      }
      const size_t boff = (size_t)((t * 2 + kk) * 4) * 512;
#pragma unroll
      for (int b = 0; b < 4; ++b) {
        v8h Bh = *(const v8h*)(pbh + boff + b * 512);
        v8h Bl = *(const v8h*)(pbl + boff + b * 512);
        acc[0][b] = MFMA16(Ah0, Bh, acc[0][b]);
        acc[1][b] = MFMA16(Ah1, Bh, acc[1][b]);
        acc[0][b] = MFMA16(Al0, Bh, acc[0][b]);
        acc[1][b] = MFMA16(Al1, Bh, acc[1][b]);
        acc[0][b] = MFMA16(Ah0, Bl, acc[0][b]);
        acc[1][b] = MFMA16(Ah1, Bl, acc[1][b]);
        acc[0][b] = MFMA16(Al0, Bl, acc[0][b]);
        acc[1][b] = MFMA16(Al1, Bl, acc[1][b]);
      }
    }
    if (++jb == 3) { jb = 0; ++d; }
  }
  const size_t xbase = ((size_t)(bl * 12 + lt)) * NN;
  const size_t c1 = ((size_t)(lt * 16 + bl)) * 2;
#pragma unroll
  for (int mi = 0; mi < 2; ++mi) {
#pragma unroll
    for (int b = 0; b < 4; ++b) {
      const int o = ob + b * 16 + rs;
      float rhv[4];
#pragma unroll
      for (int r = 0; r < 4; ++r) {
        const int Rl = mi * 16 + q * 4 + r;
        const int n = n0 + Rl;
        const size_t R = (size_t)R0 + Rl;
        const float x0a = x[(xbase + n) * 2 + 0];
        const float x0b = x[(xbase + n) * 2 + 1];
        const float x1a = X1t[c1 * NN + n];
        const float x1b = X1t[(c1 + 1) * NN + n];
        const float x2a = X2t[c1 * NN + n];
        const float x2b = X2t[(c1 + 1) * NN + n];
        const float* wx = Wx + (size_t)n * 768;
        float pre = acc[mi][b][r] + bgv[(size_t)n * 128 + o]
                  + x0a * wx[o]       + x0b * wx[128 + o]
                  + x1a * wx[256 + o] + x1b * wx[384 + o]
                  + x2a * wx[512 + o] + x2b * wx[640 + o];
        const float g = 1.f / (1.f + expf(-pre));
        if (gy == 0) {
          const float rh = g * xs[R * 192 + o];
          RHs[(size_t)bl * 1572864 + (size_t)n * 64 + o] = rh;
          rhv[r] = rh;
        } else {
          ubuf[R * 64 + (o - 64)] = g;
        }
      }
      if (gy == 0) {
        const int nb = n0 + mi * 16 + q * 4;
        v4h ph, pl;
#pragma unroll
        for (int r = 0; r < 4; ++r) {
          h16 hh = (h16)rhv[r];
          ph[r] = hh;
          pl[r] = (h16)(rhv[r] - (float)hh);
        }
        *(v4h*)(HRh + (size_t)(bl * 64 + o) * 2048 + nb) = ph;
        *(v4h*)(HRl + (size_t)(bl * 64 + o) * 2048 + nb) = pl;
      }
    }
  }
}

// ---------------- MFMA cand + GRU update: 1-wave blocks, no LDS, no barriers ----------------
__global__ __launch_bounds__(64) void mcand_k(
    float* __restrict__ xs, const float* __restrict__ RHs,
    const h16* __restrict__ Bph, const h16* __restrict__ Bpl,
    const float* __restrict__ E, const float* __restrict__ bcv,
    const float* __restrict__ Wx, const float* __restrict__ x,
    const float* __restrict__ X1t, const float* __restrict__ X2t,
    const float* __restrict__ ubuf, h16* __restrict__ HRh, h16* __restrict__ HRl,
    float* __restrict__ out, int lt) {
  const int R0 = blockIdx.x * 32;
  const int bl = R0 >> 11, n0 = R0 & 2047;
  const int lane = threadIdx.x;
  const int rs = lane & 15, q = lane >> 4;
  float e0[10], e1[10];
#pragma unroll
  for (int d = 0; d < 10; ++d) {
    e0[d] = E[(size_t)(n0 + rs) * 10 + d];
    e1[d] = E[(size_t)(n0 + 16 + rs) * 10 + d];
  }
  const float* rh0 = RHs + (size_t)bl * 1572864 + (size_t)(n0 + rs) * 64;
  const float* rh1 = RHs + (size_t)bl * 1572864 + (size_t)(n0 + 16 + rs) * 64;
  const float* xs0 = xs + (size_t)(R0 + rs) * 192;
  const float* xs1 = xs + (size_t)(R0 + 16 + rs) * 192;
  const h16* pbh = Bph + lane * 8;
  const h16* pbl = Bpl + lane * 8;
  v4f acc[2][4] = {};
  int d = 0, jb = 0;
  for (int t = 0; t < 30; ++t) {
    const float ed0 = e0[d], ed1 = e1[d];
#pragma unroll
    for (int kk = 0; kk < 2; ++kk) {
      const int cq = kk * 32 + q * 8;
      const float* s0 = (jb == 0) ? (rh0 + cq) : (xs0 + jb * 64 + cq);
      const float* s1 = (jb == 0) ? (rh1 + cq) : (xs1 + jb * 64 + cq);
      v4f x00 = *(const v4f*)s0;
      v4f x01 = *(const v4f*)(s0 + 4);
      v4f x10 = *(const v4f*)s1;
      v4f x11 = *(const v4f*)(s1 + 4);
      v8h Ah0, Al0, Ah1, Al1;
#pragma unroll
      for (int i = 0; i < 4; ++i) {
        float v = x00[i] * ed0; h16 hh = (h16)v; Ah0[i] = hh; Al0[i] = (h16)(v - (float)hh);
        v = x01[i] * ed0; hh = (h16)v; Ah0[4 + i] = hh; Al0[4 + i] = (h16)(v - (float)hh);
        v = x10[i] * ed1; hh = (h16)v; Ah1[i] = hh; Al1[i] = (h16)(v - (float)hh);
        v = x11[i] * ed1; hh = (h16)v; Ah1[4 + i] = hh; Al1[4 + i] = (h16)(v - (float)hh);
      }
      const size_t boff = (size_t)((t * 2 + kk) * 4) * 512;
#pragma unroll
      for (int b = 0; b < 4; ++b) {
        v8h Bh = *(const v8h*)(pbh + boff + b * 512);
        v8h Bl = *(const v8h*)(pbl + boff + b * 512);
        acc[0][b] = MFMA16(Ah0, Bh, acc[0][b]);
        acc[1][b] = MFMA16(Ah1, Bh, acc[1][b]);
        acc[0][b] = MFMA16(Al0, Bh, acc[0][b]);
        acc[1][b] = MFMA16(Al1, Bh, acc[1][b]);
        acc[0][b] = MFMA16(Ah0, Bl, acc[0][b]);
        acc[1][b] = MFMA16(Ah1, Bl, acc[1][b]);
        acc[0][b] = MFMA16(Al0, Bl, acc[0][b]);
        acc[1][b] = MFMA16(Al1, Bl, acc[1][b]);
      }
    }
    if (++jb == 3) { jb = 0; ++d; }
  }
  const size_t xbase = ((size_t)(bl * 12 + lt)) * NN;
  const size_t c1 = ((size_t)(lt * 16 + bl)) * 2;
#pragma unroll
  for (int mi = 0; mi < 2; ++mi) {
#pragma unroll
    for (int b = 0; b < 4; ++b) {
      const int o = b * 16 + rs;
      float hnv[4];
#pragma unroll
      for (int r = 0; r < 4; ++r) {
        const int Rl = mi * 16 + q * 4 + r;
        const int n = n0 + Rl;
        const size_t R = (size_t)R0 + Rl;
        const float x0a = x[(xbase + n) * 2 + 0];
        const float x0b = x[(xbase + n) * 2 + 1];
        const float x1a = X1t[c1 * NN + n];
        const float x1b = X1t[(c1 + 1) * NN + n];
        const float x2a = X2t[c1 * NN + n];
        const float x2b = X2t[(c1 + 1) * NN + n];
        const float* wx = Wx + (size_t)n * 384;
        float pre = acc[mi][b][r] + bcv[(size_t)n * 64 + o]
                  + x0a * wx[o]       + x0b * wx[64 + o]
                  + x1a * wx[128 + o] + x1b * wx[192 + o]
                  + x2a * wx[256 + o] + x2b * wx[320 + o];
        const float cv = tanhf(pre);
        const float u = ubuf[R * 64 + o];
        const float hold = xs[R * 192 + o];
        const float hn = u * hold + (1.f - u) * cv;
        hnv[r] = hn;
        xs[R * 192 + o] = hn;
        out[(xbase + n) * 64 + o] = hn;
      }
      const int nb = n0 + mi * 16 + q * 4;
      v4h ph, pl;
#pragma unroll
      for (int r = 0; r < 4; ++r) {
        h16 hh = (h16)hnv[r];
        ph[r] = hh;
        pl[r] = (h16)(hnv[r] - (float)hh);
      }
      *(v4h*)(HRh + (size_t)(bl * 64 + o) * 2048 + nb) = ph;
      *(v4h*)(HRl + (size_t)(bl * 64 + o) * 2048 + nb) = pl;
    }
  }
}

// ---------------- h_n gather: xs slot0 -> out (overwrites ubuf region, last) ----------------
__global__ void hn_gather_k(const float* __restrict__ xs, float* __restrict__ dst) {
  int i = blockIdx.x * 256 + threadIdx.x;   // 2,097,152
  dst[i] = xs[(size_t)(i >> 6) * 192 + (i & 63)];
}

// ---------------- launch ----------------
extern "C" void kernel_launch(void* const* d_in, const int* in_sizes, int n_in,
                              void* d_out, int out_size, void* d_ws, size_t ws_size,
                              hipStream_t stream) {
  float* out = (float*)d_out;

  const bool in_ok = (n_in == 7) &&
      in_sizes[0] == 786432 && in_sizes[1] == 20480 && in_sizes[2] == 4194304 &&
      in_sizes[3] == 253440 && in_sizes[4] == 1280 &&
      in_sizes[5] == 126720 && in_sizes[6] == 640 && out_size == 27262976;
  if (!in_ok) {
    fill_k<<<(out_size + 255) / 256, 256, 0, stream>>>(out, 77.0f, (size_t)out_size);
    return;
  }
  constexpr size_t NEED = 85884928;
  if (ws_size < NEED) {
    fill_k<<<106496, 256, 0, stream>>>(out, 42.0f, 27262976);
    return;
  }

  const float* x   = (const float*)d_in[0];
  const float* E   = (const float*)d_in[1];
  const float* A   = (const float*)d_in[2];
  const float* Wgp = (const float*)d_in[3];
  const float* bgp = (const float*)d_in[4];
  const float* Wcp = (const float*)d_in[5];
  const float* bcp = (const float*)d_in[6];

  char* p = (char*)d_ws;
  auto carve = [&](size_t bytes) { char* r = p; p += bytes; return r; };
  // shared
  h16*   ABh  = (h16*)carve(16777216);   // [A*2048 ; A2half] split hi [4096][2048]
  h16*   ABl  = (h16*)carve(16777216);
  float* X1t  = (float*)carve(3145728);  // A@x   [384][2048] fp32
  float* X2t  = (float*)carve(3145728);  // A@(A@x)
  h16*   WgTh = (h16*)carve(491520);     // packed gate W split hi [2 gy][30][2][4][64][8]
  h16*   WgTl = (h16*)carve(491520);
  h16*   WcTh = (h16*)carve(245760);     // packed cand W [30][2][4][64][8]
  h16*   WcTl = (h16*)carve(245760);
  float* WxG  = (float*)carve(6291456);  // [2048][6][128]
  float* WxC  = (float*)carve(3145728);  // [2048][6][64]
  float* bgv  = (float*)carve(1048576);
  float* bcv  = (float*)carve(524288);
  // loop scratch -> total exactly 85,884,928
  float* xs   = (float*)carve(25165824); // [32768][192] fp32: [h | y1 | y2]
  h16*   HRh  = (h16*)carve(4194304);    // h / rh split, feature-major [1024][2048]
  h16*   HRl  = (h16*)carve(4194304);
  // rh fp32 lives in d_out's lt=11 slices (dead until mcand@lt=11 overwrites in place)
  float* RHs  = out + 1441792;           // base = 11*131072; +bl*1572864 + n*64 + o
  // u gate lives in d_out's h_n region (dead until hn_gather at the very end)
  float* ubuf = out + 25165824;          // 8,388,608 B
  // prep-phase aliases inside xs (dead before the loop memset)
  h16* AsTh = (h16*)xs;                               // 8,388,608
  h16* AsTl = (h16*)((char*)xs + 8388608);            // 8,388,608
  h16* X0h  = (h16*)((char*)xs + 16777216);           // 1,572,864
  h16* X0l  = (h16*)((char*)xs + 18350080);
  h16* X1h  = (h16*)((char*)xs + 19922944);
  h16* X1l  = (h16*)((char*)xs + 21495808);

  prep_Asplit_k<<<16384, 256, 0, stream>>>(A, ABh, ABl);
  prep_AsTsplit_k<<<16384, 256, 0, stream>>>(A, AsTh, AsTl);
  prep_wpack_k<128><<<960, 256, 0, stream>>>(Wgp, WgTh, WgTl);
  prep_wpack_k<64><<<480, 256, 0, stream>>>(Wcp, WcTh, WcTl);
  prep_wx_k<128><<<6144, 256, 0, stream>>>(E, Wgp, WxG);
  prep_wx_k<64><<<3072, 256, 0, stream>>>(E, Wcp, WxC);
  prep_b_k<128><<<1024, 256, 0, stream>>>(E, bgp, bgv);
  prep_b_k<64><<<512, 256, 0, stream>>>(E, bcp, bcv);
  // A2half = INV_N * As@As  -> AB rows 2048..4095 (split pair)
  sgemm_k<2><<<dim3(32, 32), 256, 0, stream>>>(ABh, ABl, AsTh, AsTl,
                                               nullptr, ABh + 4194304, ABl + 4194304,
                                               nullptr, 0);
  // x-path (chained, unchanged arithmetic)
  prep_x0split_k<<<3072, 256, 0, stream>>>(x, X0h, X0l);
  sgemm_k<3><<<dim3(6, 32), 256, 0, stream>>>(X0h, X0l, ABh, ABl, X1t, X1h, X1l, nullptr, 0);
  sgemm_k<1><<<dim3(6, 32), 256, 0, stream>>>(X1h, X1l, ABh, ABl, X2t, nullptr, nullptr, nullptr, 0);

  hipMemsetAsync(xs, 0, 25165824, stream);
  hipMemsetAsync(HRh, 0, 4194304, stream);
  hipMemsetAsync(HRl, 0, 4194304, stream);
  for (int lt = 0; lt < 12; ++lt) {
    // stacked conv: y1 (cols 0-2047) and y2 (cols 2048-4095) in one dispatch
    sgemm_k<4><<<dim3(16, 64), 256, 0, stream>>>(HRh, HRl, ABh, ABl,
                                                 nullptr, nullptr, nullptr, xs, 64);
    mgate_k<<<dim3(1024, 2), 64, 0, stream>>>(xs, WgTh, WgTl, E, bgv, WxG, x, X1t, X2t,
                                              RHs, ubuf, HRh, HRl, lt);
    sgemm_k<4><<<dim3(16, 64), 256, 0, stream>>>(HRh, HRl, ABh, ABl,
                                                 nullptr, nullptr, nullptr, xs, 64);
    mcand_k<<<1024, 64, 0, stream>>>(xs, RHs, WcTh, WcTl, E, bcv, WxC, x, X1t, X2t,
                                     ubuf, HRh, HRl, out, lt);
  }
  hn_gather_k<<<8192, 256, 0, stream>>>(xs, out + 25165824);
}

// Round 16
// 3600.375 us; speedup vs baseline: 1.1628x; 1.1628x over previous
//
#include <hip/hip_runtime.h>
#include <cstdint>
#include <cstddef>

typedef _Float16 h16;
typedef h16 v8h __attribute__((ext_vector_type(8)));
typedef h16 v4h __attribute__((ext_vector_type(4)));
typedef float v4f __attribute__((ext_vector_type(4)));

constexpr int NN = 2048;
constexpr float INV_N = 1.0f / 2048.0f;
constexpr int LP = 72;  // LDS row stride in halves (64 + 8 pad)

#define MFMA16(a, b, c) __builtin_amdgcn_mfma_f32_16x16x32_f16((a), (b), (c), 0, 0, 0)

// ---------------- diagnostic fill ----------------
__global__ void fill_k(float* __restrict__ o, float v, size_t ntot) {
  size_t i = (size_t)blockIdx.x * 256 + threadIdx.x;
  if (i < ntot) o[i] = v;
}

// ---------------- prep kernels (r15 verbatim) ----------------

__global__ void prep_Asplit_k(const float* __restrict__ A,
                              h16* __restrict__ hi, h16* __restrict__ lo) {
  int tid = blockIdx.x * 256 + threadIdx.x;   // 4M
  float v = A[tid] * 2048.0f;
  h16 h = (h16)v;
  hi[tid] = h;
  lo[tid] = (h16)(v - (float)h);
}

__global__ void prep_AsTsplit_k(const float* __restrict__ A,
                                h16* __restrict__ hi, h16* __restrict__ lo) {
  int tid = blockIdx.x * 256 + threadIdx.x;   // 4M
  int t = tid & 2047, j = tid >> 11;
  float v = A[(size_t)t * NN + j] * 2048.0f;
  h16 h = (h16)v;
  hi[(size_t)j * NN + t] = h;
  lo[(size_t)j * NN + t] = (h16)(v - (float)h);
}

__global__ void prep_x0split_k(const float* __restrict__ x,
                               h16* __restrict__ hi, h16* __restrict__ lo) {
  int tid = blockIdx.x * 256 + threadIdx.x;   // 384*2048
  int n = tid & 2047, c = tid >> 11;
  int ii = c & 1, b = (c >> 1) & 15, lt = c >> 5;
  float v = x[(((size_t)(b * 12 + lt)) * NN + n) * 2 + ii];
  h16 h = (h16)v;
  hi[tid] = h;
  lo[tid] = (h16)(v - (float)h);
}

// Packed folded pool weights in MFMA-fragment order:
// dest tid = (((g*30 + t)*2 + kk)*4 + b)*512 + lane*8 + c
template<int CO>
__global__ void prep_wpack_k(const float* __restrict__ Wp,
                             h16* __restrict__ Ph, h16* __restrict__ Pl) {
  int tid = blockIdx.x * 256 + threadIdx.x;   // CO*1920 elements
  int c = tid & 7;
  int ln = (tid >> 3) & 63;
  int rest = tid >> 9;
  int b = rest & 3;
  int kk = (rest >> 2) & 1;
  int r3 = rest >> 3;           // g*30 + t
  int t = r3 % 30;
  int g = r3 / 30;
  int o = g * 64 + b * 16 + (ln & 15);
  int kcol = (t / 3) * 192 + (t % 3) * 64 + kk * 32 + (ln >> 4) * 8 + c;
  int d = kcol / 192, rem = kcol - d * 192;
  int jb = rem >> 6, i = rem & 63;
  float v;
  if (jb == 0)
    v = Wp[((size_t)((d * 3 + 0) * 66 + i)) * CO + o] -
        Wp[((size_t)((d * 3 + 2) * 66 + i)) * CO + o];
  else if (jb == 1)
    v = Wp[((size_t)((d * 3 + 1) * 66 + i)) * CO + o];
  else
    v = 2.f * Wp[((size_t)((d * 3 + 2) * 66 + i)) * CO + o];
  h16 h = (h16)v;
  Ph[tid] = h;
  Pl[tid] = (h16)(v - (float)h);
}

template<int CO>
__global__ void prep_wx_k(const float* __restrict__ E, const float* __restrict__ Wp,
                          float* __restrict__ Wx) {
  int tid = blockIdx.x * 256 + threadIdx.x;   // 2048*6*CO
  int o = tid & (CO - 1), t6 = (tid / CO) % 6, n = tid / (6 * CO);
  int k = t6 >> 1, ii = t6 & 1;
  float s = 0.f;
  for (int d = 0; d < 10; ++d) {
    float p0 = Wp[((size_t)((d * 3 + 0) * 66 + 64 + ii)) * CO + o];
    float p1 = Wp[((size_t)((d * 3 + 1) * 66 + 64 + ii)) * CO + o];
    float p2 = Wp[((size_t)((d * 3 + 2) * 66 + 64 + ii)) * CO + o];
    float v = (k == 0) ? (p0 - p2) : (k == 1 ? p1 : 2.f * p2);
    s += E[n * 10 + d] * v;
  }
  Wx[tid] = s;
}

template<int CO>
__global__ void prep_b_k(const float* __restrict__ E, const float* __restrict__ bp,
                         float* __restrict__ bv) {
  int tid = blockIdx.x * 256 + threadIdx.x;   // 2048*CO
  int o = tid & (CO - 1), n = tid / CO;
  float s = 0.f;
  for (int d = 0; d < 10; ++d) s += E[n * 10 + d] * bp[d * CO + o];
  bv[tid] = s;
}

// ---------------- split-fp16 MFMA SpMM, BM=64/BN=64, 256 thr (r14 verbatim) ----------------
template<int OM>
__global__ __launch_bounds__(256, 4) void sgemm_k(
    const h16* __restrict__ Ih, const h16* __restrict__ Il,
    const h16* __restrict__ Bh, const h16* __restrict__ Bl,
    float* __restrict__ oF, h16* __restrict__ oH, h16* __restrict__ oL,
    float* __restrict__ xsv, int xoff) {
  const int m0 = blockIdx.x * 64, n0 = blockIdx.y * 64;
  __shared__ __align__(16) h16 sAh[64 * LP], sAl[64 * LP];
  __shared__ __align__(16) h16 sBh[64 * LP], sBl[64 * LP];
  const int tid = threadIdx.x, lane = tid & 63, w = tid >> 6;
  const int wm = w >> 1, wn = w & 1;
  v4f acc[2][2] = {};
  const int sr = tid >> 2, sc = (tid & 3) * 16;
  v8h rah0 = *(const v8h*)(Ih + (size_t)(m0 + sr) * NN + sc);
  v8h rah1 = *(const v8h*)(Ih + (size_t)(m0 + sr) * NN + sc + 8);
  v8h ral0 = *(const v8h*)(Il + (size_t)(m0 + sr) * NN + sc);
  v8h ral1 = *(const v8h*)(Il + (size_t)(m0 + sr) * NN + sc + 8);
  v8h rbh0 = *(const v8h*)(Bh + (size_t)(n0 + sr) * NN + sc);
  v8h rbh1 = *(const v8h*)(Bh + (size_t)(n0 + sr) * NN + sc + 8);
  v8h rbl0 = *(const v8h*)(Bl + (size_t)(n0 + sr) * NN + sc);
  v8h rbl1 = *(const v8h*)(Bl + (size_t)(n0 + sr) * NN + sc + 8);
  for (int kt = 0; kt < NN; kt += 64) {
    __syncthreads();
    *(v8h*)(sAh + sr * LP + sc) = rah0;
    *(v8h*)(sAh + sr * LP + sc + 8) = rah1;
    *(v8h*)(sAl + sr * LP + sc) = ral0;
    *(v8h*)(sAl + sr * LP + sc + 8) = ral1;
    *(v8h*)(sBh + sr * LP + sc) = rbh0;
    *(v8h*)(sBh + sr * LP + sc + 8) = rbh1;
    *(v8h*)(sBl + sr * LP + sc) = rbl0;
    *(v8h*)(sBl + sr * LP + sc + 8) = rbl1;
    __syncthreads();
    if (kt + 64 < NN) {
      const int k2 = kt + 64 + sc;
      rah0 = *(const v8h*)(Ih + (size_t)(m0 + sr) * NN + k2);
      rah1 = *(const v8h*)(Ih + (size_t)(m0 + sr) * NN + k2 + 8);
      ral0 = *(const v8h*)(Il + (size_t)(m0 + sr) * NN + k2);
      ral1 = *(const v8h*)(Il + (size_t)(m0 + sr) * NN + k2 + 8);
      rbh0 = *(const v8h*)(Bh + (size_t)(n0 + sr) * NN + k2);
      rbh1 = *(const v8h*)(Bh + (size_t)(n0 + sr) * NN + k2 + 8);
      rbl0 = *(const v8h*)(Bl + (size_t)(n0 + sr) * NN + k2);
      rbl1 = *(const v8h*)(Bl + (size_t)(n0 + sr) * NN + k2 + 8);
    }
#pragma unroll
    for (int kk = 0; kk < 2; ++kk) {
      const int ko = kk * 32 + (lane >> 4) * 8;
      const int rs = lane & 15;
      v8h Ah0 = *(const v8h*)(sAh + (wm * 32 + rs) * LP + ko);
      v8h Ah1 = *(const v8h*)(sAh + (wm * 32 + 16 + rs) * LP + ko);
      v8h Al0 = *(const v8h*)(sAl + (wm * 32 + rs) * LP + ko);
      v8h Al1 = *(const v8h*)(sAl + (wm * 32 + 16 + rs) * LP + ko);
      v8h Bh0 = *(const v8h*)(sBh + (wn * 32 + rs) * LP + ko);
      v8h Bh1 = *(const v8h*)(sBh + (wn * 32 + 16 + rs) * LP + ko);
      v8h Bl0 = *(const v8h*)(sBl + (wn * 32 + rs) * LP + ko);
      v8h Bl1 = *(const v8h*)(sBl + (wn * 32 + 16 + rs) * LP + ko);
      acc[0][0] = MFMA16(Ah0, Bh0, acc[0][0]);
      acc[0][1] = MFMA16(Ah0, Bh1, acc[0][1]);
      acc[1][0] = MFMA16(Ah1, Bh0, acc[1][0]);
      acc[1][1] = MFMA16(Ah1, Bh1, acc[1][1]);
      acc[0][0] = MFMA16(Al0, Bh0, acc[0][0]);
      acc[0][1] = MFMA16(Al0, Bh1, acc[0][1]);
      acc[1][0] = MFMA16(Al1, Bh0, acc[1][0]);
      acc[1][1] = MFMA16(Al1, Bh1, acc[1][1]);
      acc[0][0] = MFMA16(Ah0, Bl0, acc[0][0]);
      acc[0][1] = MFMA16(Ah0, Bl1, acc[0][1]);
      acc[1][0] = MFMA16(Ah1, Bl0, acc[1][0]);
      acc[1][1] = MFMA16(Ah1, Bl1, acc[1][1]);
    }
  }
  const int l15 = lane & 15, l4 = (lane >> 4) * 4;
#pragma unroll
  for (int ni = 0; ni < 2; ++ni) {
    const int n = n0 + wn * 32 + ni * 16 + l15;
#pragma unroll
    for (int mi = 0; mi < 2; ++mi) {
      const int cb = m0 + wm * 32 + mi * 16 + l4;
      float vv[4];
#pragma unroll
      for (int r = 0; r < 4; ++r) {
        vv[r] = acc[mi][ni][r] * INV_N;
        if constexpr (OM & 1) oF[(size_t)(cb + r) * NN + n] = vv[r];
        if constexpr (OM & 2) {
          h16 h = (h16)vv[r];
          oH[(size_t)(cb + r) * NN + n] = h;
          oL[(size_t)(cb + r) * NN + n] = (h16)(vv[r] - (float)h);
        }
      }
      if constexpr (OM & 4) {
        const int n2 = n & 2047;
        const int xo = xoff + ((n >> 11) << 6);
        v4f pv = {vv[0], vv[1], vv[2], vv[3]};
        *(v4f*)(xsv + ((size_t)(cb >> 6) * 2048 + n2) * 192 + xo + (cb & 63)) = pv;
      }
    }
  }
}

// ---------------- MFMA gate: A dbuf-LDS (1 barrier/t), B direct packed-global ----------------
// grid 1024, 256 thr (4 waves); wave w owns o in [w*32, w*32+32).
__global__ __launch_bounds__(256) void mgate_k(
    const float* __restrict__ xs, const h16* __restrict__ Bph, const h16* __restrict__ Bpl,
    const float* __restrict__ E, const float* __restrict__ bgv,
    const float* __restrict__ Wx, const float* __restrict__ x,
    const float* __restrict__ X1t, const float* __restrict__ X2t,
    float* __restrict__ RHs, float* __restrict__ ubuf,
    h16* __restrict__ HRh, h16* __restrict__ HRl, int lt) {
  const int R0 = blockIdx.x * 32;
  const int bl = R0 >> 11, n0 = R0 & 2047;
  __shared__ __align__(16) h16 sAh[2 * 32 * LP], sAl[2 * 32 * LP];
  const int tid = threadIdx.x, lane = tid & 63, w = tid >> 6;
  const int rs = lane & 15, q = lane >> 4;
  const int g = w >> 1, bsel = (w & 1) * 2, ob = w * 32;
  const int asr = tid >> 3, asc = (tid & 7) * 8;
  const float* arow = xs + (size_t)(R0 + asr) * 192 + asc;
  const float* erow = E + (size_t)(n0 + asr) * 10;
  const h16* pbh = Bph + (size_t)(g * 30) * 4096 + lane * 8;
  const h16* pbl = Bpl + (size_t)(g * 30) * 4096 + lane * 8;
  v4f acc[2][2] = {};
  int d = 0, jb = 0;
  for (int t = 0; t < 30; ++t) {
    v8h Bh[2][2], Bl[2][2];
#pragma unroll
    for (int kk = 0; kk < 2; ++kk)
#pragma unroll
      for (int bi = 0; bi < 2; ++bi) {
        const size_t off = (size_t)t * 4096 + kk * 2048 + (bsel + bi) * 512;
        Bh[kk][bi] = *(const v8h*)(pbh + off);
        Bl[kk][bi] = *(const v8h*)(pbl + off);
      }
    const float e = erow[d];
    v4f a0 = *(const v4f*)(arow + jb * 64);
    v4f a1 = *(const v4f*)(arow + jb * 64 + 4);
    v8h ah, al;
#pragma unroll
    for (int i = 0; i < 4; ++i) {
      float v = a0[i] * e; h16 hh = (h16)v; ah[i] = hh; al[i] = (h16)(v - (float)hh);
      v = a1[i] * e; hh = (h16)v; ah[4 + i] = hh; al[4 + i] = (h16)(v - (float)hh);
    }
    const int bo = (t & 1) * (32 * LP);
    *(v8h*)(sAh + bo + asr * LP + asc) = ah;
    *(v8h*)(sAl + bo + asr * LP + asc) = al;
    __syncthreads();
#pragma unroll
    for (int kk = 0; kk < 2; ++kk) {
      const int ko = kk * 32 + q * 8;
      v8h Ah0 = *(const v8h*)(sAh + bo + rs * LP + ko);
      v8h Ah1 = *(const v8h*)(sAh + bo + (16 + rs) * LP + ko);
      v8h Al0 = *(const v8h*)(sAl + bo + rs * LP + ko);
      v8h Al1 = *(const v8h*)(sAl + bo + (16 + rs) * LP + ko);
#pragma unroll
      for (int bi = 0; bi < 2; ++bi) {
        acc[0][bi] = MFMA16(Ah0, Bh[kk][bi], acc[0][bi]);
        acc[1][bi] = MFMA16(Ah1, Bh[kk][bi], acc[1][bi]);
        acc[0][bi] = MFMA16(Al0, Bh[kk][bi], acc[0][bi]);
        acc[1][bi] = MFMA16(Al1, Bh[kk][bi], acc[1][bi]);
        acc[0][bi] = MFMA16(Ah0, Bl[kk][bi], acc[0][bi]);
        acc[1][bi] = MFMA16(Ah1, Bl[kk][bi], acc[1][bi]);
        acc[0][bi] = MFMA16(Al0, Bl[kk][bi], acc[0][bi]);
        acc[1][bi] = MFMA16(Al1, Bl[kk][bi], acc[1][bi]);
      }
    }
    if (++jb == 3) { jb = 0; ++d; }
  }
  const size_t xbase = ((size_t)(bl * 12 + lt)) * NN;
  const size_t c1 = ((size_t)(lt * 16 + bl)) * 2;
#pragma unroll
  for (int mi = 0; mi < 2; ++mi) {
#pragma unroll
    for (int bi = 0; bi < 2; ++bi) {
      const int o = ob + bi * 16 + rs;
      float rhv[4];
#pragma unroll
      for (int r = 0; r < 4; ++r) {
        const int Rl = mi * 16 + q * 4 + r;
        const int n = n0 + Rl;
        const size_t R = (size_t)R0 + Rl;
        const float x0a = x[(xbase + n) * 2 + 0];
        const float x0b = x[(xbase + n) * 2 + 1];
        const float x1a = X1t[c1 * NN + n];
        const float x1b = X1t[(c1 + 1) * NN + n];
        const float x2a = X2t[c1 * NN + n];
        const float x2b = X2t[(c1 + 1) * NN + n];
        const float* wx = Wx + (size_t)n * 768;
        float pre = acc[mi][bi][r] + bgv[(size_t)n * 128 + o]
                  + x0a * wx[o]       + x0b * wx[128 + o]
                  + x1a * wx[256 + o] + x1b * wx[384 + o]
                  + x2a * wx[512 + o] + x2b * wx[640 + o];
        const float gg = 1.f / (1.f + expf(-pre));
        if (o < 64) {
          const float rh = gg * xs[R * 192 + o];
          RHs[(size_t)bl * 1572864 + (size_t)n * 64 + o] = rh;
          rhv[r] = rh;
        } else {
          ubuf[R * 64 + (o - 64)] = gg;
        }
      }
      if (o < 64) {
        const int nb = n0 + mi * 16 + q * 4;
        v4h ph, pl;
#pragma unroll
        for (int r = 0; r < 4; ++r) {
          h16 hh = (h16)rhv[r];
          ph[r] = hh;
          pl[r] = (h16)(rhv[r] - (float)hh);
        }
        *(v4h*)(HRh + (size_t)(bl * 64 + o) * 2048 + nb) = ph;
        *(v4h*)(HRl + (size_t)(bl * 64 + o) * 2048 + nb) = pl;
      }
    }
  }
}

// ---------------- MFMA cand + GRU update: A dbuf-LDS, B direct packed-global ----------------
// grid 1024, 256 thr (4 waves); wave w owns o in [w*16, w*16+16).
__global__ __launch_bounds__(256) void mcand_k(
    float* __restrict__ xs, const float* __restrict__ RHs,
    const h16* __restrict__ Bph, const h16* __restrict__ Bpl,
    const float* __restrict__ E, const float* __restrict__ bcv,
    const float* __restrict__ Wx, const float* __restrict__ x,
    const float* __restrict__ X1t, const float* __restrict__ X2t,
    const float* __restrict__ ubuf, h16* __restrict__ HRh, h16* __restrict__ HRl,
    float* __restrict__ out, int lt) {
  const int R0 = blockIdx.x * 32;
  const int bl = R0 >> 11, n0 = R0 & 2047;
  __shared__ __align__(16) h16 sAh[2 * 32 * LP], sAl[2 * 32 * LP];
  const int tid = threadIdx.x, lane = tid & 63, w = tid >> 6;
  const int rs = lane & 15, q = lane >> 4;
  const int asr = tid >> 3, asc = (tid & 7) * 8;
  const float* erow = E + (size_t)(n0 + asr) * 10;
  const float* rhrow = RHs + (size_t)bl * 1572864 + (size_t)(n0 + asr) * 64 + asc;
  const float* xsrow = xs + (size_t)(R0 + asr) * 192 + asc;
  const h16* pbh = Bph + lane * 8;
  const h16* pbl = Bpl + lane * 8;
  v4f acc[2] = {};
  int d = 0, jb = 0;
  for (int t = 0; t < 30; ++t) {
    v8h Bh[2], Bl[2];
#pragma unroll
    for (int kk = 0; kk < 2; ++kk) {
      const size_t off = (size_t)t * 4096 + kk * 2048 + w * 512;
      Bh[kk] = *(const v8h*)(pbh + off);
      Bl[kk] = *(const v8h*)(pbl + off);
    }
    const float e = erow[d];
    const float* src = (jb == 0) ? rhrow : (xsrow + jb * 64);
    v4f a0 = *(const v4f*)src;
    v4f a1 = *(const v4f*)(src + 4);
    v8h ah, al;
#pragma unroll
    for (int i = 0; i < 4; ++i) {
      float v = a0[i] * e; h16 hh = (h16)v; ah[i] = hh; al[i] = (h16)(v - (float)hh);
      v = a1[i] * e; hh = (h16)v; ah[4 + i] = hh; al[4 + i] = (h16)(v - (float)hh);
    }
    const int bo = (t & 1) * (32 * LP);
    *(v8h*)(sAh + bo + asr * LP + asc) = ah;
    *(v8h*)(sAl + bo + asr * LP + asc) = al;
    __syncthreads();
#pragma unroll
    for (int kk = 0; kk < 2; ++kk) {
      const int ko = kk * 32 + q * 8;
      v8h Ah0 = *(const v8h*)(sAh + bo + rs * LP + ko);
      v8h Ah1 = *(const v8h*)(sAh + bo + (16 + rs) * LP + ko);
      v8h Al0 = *(const v8h*)(sAl + bo + rs * LP + ko);
      v8h Al1 = *(const v8h*)(sAl + bo + (16 + rs) * LP + ko);
      acc[0] = MFMA16(Ah0, Bh[kk], acc[0]);
      acc[1] = MFMA16(Ah1, Bh[kk], acc[1]);
      acc[0] = MFMA16(Al0, Bh[kk], acc[0]);
      acc[1] = MFMA16(Al1, Bh[kk], acc[1]);
      acc[0] = MFMA16(Ah0, Bl[kk], acc[0]);
      acc[1] = MFMA16(Ah1, Bl[kk], acc[1]);
      acc[0] = MFMA16(Al0, Bl[kk], acc[0]);
      acc[1] = MFMA16(Al1, Bl[kk], acc[1]);
    }
    if (++jb == 3) { jb = 0; ++d; }
  }
  const size_t xbase = ((size_t)(bl * 12 + lt)) * NN;
  const size_t c1 = ((size_t)(lt * 16 + bl)) * 2;
  const int o = w * 16 + rs;
#pragma unroll
  for (int mi = 0; mi < 2; ++mi) {
    float hnv[4];
#pragma unroll
    for (int r = 0; r < 4; ++r) {
      const int Rl = mi * 16 + q * 4 + r;
      const int n = n0 + Rl;
      const size_t R = (size_t)R0 + Rl;
      const float x0a = x[(xbase + n) * 2 + 0];
      const float x0b = x[(xbase + n) * 2 + 1];
      const float x1a = X1t[c1 * NN + n];
      const float x1b = X1t[(c1 + 1) * NN + n];
      const float x2a = X2t[c1 * NN + n];
      const float x2b = X2t[(c1 + 1) * NN + n];
      const float* wx = Wx + (size_t)n * 384;
      float pre = acc[mi][r] + bcv[(size_t)n * 64 + o]
                + x0a * wx[o]       + x0b * wx[64 + o]
                + x1a * wx[128 + o] + x1b * wx[192 + o]
                + x2a * wx[256 + o] + x2b * wx[320 + o];
      const float cv = tanhf(pre);
      const float u = ubuf[R * 64 + o];
      const float hold = xs[R * 192 + o];
      const float hn = u * hold + (1.f - u) * cv;
      hnv[r] = hn;
      xs[R * 192 + o] = hn;
      out[(xbase + n) * 64 + o] = hn;
    }
    const int nb = n0 + mi * 16 + q * 4;
    v4h ph, pl;
#pragma unroll
    for (int r = 0; r < 4; ++r) {
      h16 hh = (h16)hnv[r];
      ph[r] = hh;
      pl[r] = (h16)(hnv[r] - (float)hh);
    }
    *(v4h*)(HRh + (size_t)(bl * 64 + o) * 2048 + nb) = ph;
    *(v4h*)(HRl + (size_t)(bl * 64 + o) * 2048 + nb) = pl;
  }
}

// ---------------- h_n gather: xs slot0 -> out (overwrites ubuf region, last) ----------------
__global__ void hn_gather_k(const float* __restrict__ xs, float* __restrict__ dst) {
  int i = blockIdx.x * 256 + threadIdx.x;   // 2,097,152
  dst[i] = xs[(size_t)(i >> 6) * 192 + (i & 63)];
}

// ---------------- launch ----------------
extern "C" void kernel_launch(void* const* d_in, const int* in_sizes, int n_in,
                              void* d_out, int out_size, void* d_ws, size_t ws_size,
                              hipStream_t stream) {
  float* out = (float*)d_out;

  const bool in_ok = (n_in == 7) &&
      in_sizes[0] == 786432 && in_sizes[1] == 20480 && in_sizes[2] == 4194304 &&
      in_sizes[3] == 253440 && in_sizes[4] == 1280 &&
      in_sizes[5] == 126720 && in_sizes[6] == 640 && out_size == 27262976;
  if (!in_ok) {
    fill_k<<<(out_size + 255) / 256, 256, 0, stream>>>(out, 77.0f, (size_t)out_size);
    return;
  }
  constexpr size_t NEED = 85884928;
  if (ws_size < NEED) {
    fill_k<<<106496, 256, 0, stream>>>(out, 42.0f, 27262976);
    return;
  }

  const float* x   = (const float*)d_in[0];
  const float* E   = (const float*)d_in[1];
  const float* A   = (const float*)d_in[2];
  const float* Wgp = (const float*)d_in[3];
  const float* bgp = (const float*)d_in[4];
  const float* Wcp = (const float*)d_in[5];
  const float* bcp = (const float*)d_in[6];

  char* p = (char*)d_ws;
  auto carve = [&](size_t bytes) { char* r = p; p += bytes; return r; };
  // shared
  h16*   ABh  = (h16*)carve(16777216);   // [A*2048 ; A2half] split hi [4096][2048]
  h16*   ABl  = (h16*)carve(16777216);
  float* X1t  = (float*)carve(3145728);  // A@x   [384][2048] fp32
  float* X2t  = (float*)carve(3145728);  // A@(A@x)
  h16*   WgTh = (h16*)carve(491520);     // packed gate W split hi [2 g][30][2][4][64][8]
  h16*   WgTl = (h16*)carve(491520);
  h16*   WcTh = (h16*)carve(245760);     // packed cand W [30][2][4][64][8]
  h16*   WcTl = (h16*)carve(245760);
  float* WxG  = (float*)carve(6291456);  // [2048][6][128]
  float* WxC  = (float*)carve(3145728);  // [2048][6][64]
  float* bgv  = (float*)carve(1048576);
  float* bcv  = (float*)carve(524288);
  // loop scratch -> total exactly 85,884,928
  float* xs   = (float*)carve(25165824); // [32768][192] fp32: [h | y1 | y2]
  h16*   HRh  = (h16*)carve(4194304);    // h / rh split, feature-major [1024][2048]
  h16*   HRl  = (h16*)carve(4194304);
  // rh fp32 lives in d_out's lt=11 slices (dead until mcand@lt=11 overwrites in place)
  float* RHs  = out + 1441792;           // base = 11*131072; +bl*1572864 + n*64 + o
  // u gate lives in d_out's h_n region (dead until hn_gather at the very end)
  float* ubuf = out + 25165824;          // 8,388,608 B
  // prep-phase aliases inside xs (dead before the loop memset)
  h16* AsTh = (h16*)xs;                               // 8,388,608
  h16* AsTl = (h16*)((char*)xs + 8388608);            // 8,388,608
  h16* X0h  = (h16*)((char*)xs + 16777216);           // 1,572,864
  h16* X0l  = (h16*)((char*)xs + 18350080);
  h16* X1h  = (h16*)((char*)xs + 19922944);
  h16* X1l  = (h16*)((char*)xs + 21495808);

  prep_Asplit_k<<<16384, 256, 0, stream>>>(A, ABh, ABl);
  prep_AsTsplit_k<<<16384, 256, 0, stream>>>(A, AsTh, AsTl);
  prep_wpack_k<128><<<960, 256, 0, stream>>>(Wgp, WgTh, WgTl);
  prep_wpack_k<64><<<480, 256, 0, stream>>>(Wcp, WcTh, WcTl);
  prep_wx_k<128><<<6144, 256, 0, stream>>>(E, Wgp, WxG);
  prep_wx_k<64><<<3072, 256, 0, stream>>>(E, Wcp, WxC);
  prep_b_k<128><<<1024, 256, 0, stream>>>(E, bgp, bgv);
  prep_b_k<64><<<512, 256, 0, stream>>>(E, bcp, bcv);
  // A2half = INV_N * As@As  -> AB rows 2048..4095 (split pair)
  sgemm_k<2><<<dim3(32, 32), 256, 0, stream>>>(ABh, ABl, AsTh, AsTl,
                                               nullptr, ABh + 4194304, ABl + 4194304,
                                               nullptr, 0);
  // x-path (chained, unchanged arithmetic)
  prep_x0split_k<<<3072, 256, 0, stream>>>(x, X0h, X0l);
  sgemm_k<3><<<dim3(6, 32), 256, 0, stream>>>(X0h, X0l, ABh, ABl, X1t, X1h, X1l, nullptr, 0);
  sgemm_k<1><<<dim3(6, 32), 256, 0, stream>>>(X1h, X1l, ABh, ABl, X2t, nullptr, nullptr, nullptr, 0);

  hipMemsetAsync(xs, 0, 25165824, stream);
  hipMemsetAsync(HRh, 0, 4194304, stream);
  hipMemsetAsync(HRl, 0, 4194304, stream);
  for (int lt = 0; lt < 12; ++lt) {
    // stacked conv: y1 (cols 0-2047) and y2 (cols 2048-4095) in one dispatch
    sgemm_k<4><<<dim3(16, 64), 256, 0, stream>>>(HRh, HRl, ABh, ABl,
                                                 nullptr, nullptr, nullptr, xs, 64);
    mgate_k<<<1024, 256, 0, stream>>>(xs, WgTh, WgTl, E, bgv, WxG, x, X1t, X2t,
                                      RHs, ubuf, HRh, HRl, lt);
    sgemm_k<4><<<dim3(16, 64), 256, 0, stream>>>(HRh, HRl, ABh, ABl,
                                                 nullptr, nullptr, nullptr, xs, 64);
    mcand_k<<<1024, 256, 0, stream>>>(xs, RHs, WcTh, WcTl, E, bcv, WxC, x, X1t, X2t,
                                      ubuf, HRh, HRl, out, lt);
  }
  hn_gather_k<<<8192, 256, 0, stream>>>(xs, out + 25165824);
}